// Round 1
// 930.060 us; speedup vs baseline: 2.5252x; 2.5252x over previous
//
#include <hip/hip_runtime.h>
#include <hip/hip_fp16.h>
#include <math.h>

// ---- geometry ----
#define VIEWS  360
#define NDET   512
#define CH     8
#define RR     11
#define HID    176
#define OC     88
#define LPOS   (VIEWS*NDET*RR)       // 2,027,520 positions
#define NIDX   (128*128*VIEWS)       // 5,898,240 indices

#define DCHUNK 128
#define NCHUNK (NDET/DCHUNK)         // 4
#define HTROWS (DCHUNK+2)            // 130 rows: d = d0-1 .. d0+128
#define HTHALF 192                   // halves per hT row (24 x 16B granules, HID padded 176->192)
#define NMT    6                     // o-tiles of 16 (OC padded 88->96)
#define NKSTEP 18                    // 6 k-blocks x 3 conv taps

typedef _Float16 f16x8 __attribute__((ext_vector_type(8)));
typedef float    f32x4 __attribute__((ext_vector_type(4)));

// w2 pre-packed in MFMA A-fragment order: [kstep][mt][lane][8], fp16, zero-padded
__device__ __align__(16) _Float16 g_w2a[NKSTEP*NMT*64*8];

// XOR swizzle on 16B granules; same function on write and read sides.
__device__ __forceinline__ int swz(int r) { return (r ^ (r >> 3)) & 7; }

// ---------------- Kernel 0: pack w2 into fragment order ----------------
__global__ __launch_bounds__(256) void pack_w2(const float* __restrict__ w2)
{
    int idx = blockIdx.x*256 + threadIdx.x;
    if (idx >= NKSTEP*NMT*64*8) return;
    int j     = idx & 7;
    int lane  = (idx >> 3) & 63;
    int t     = idx >> 9;
    int mt    = t % NMT;
    int kstep = t / NMT;
    int kb    = kstep / 3, tap = kstep % 3;
    int o     = mt*16 + (lane & 15);           // A row  = lane&15
    int hh    = kb*32 + (lane >> 4)*8 + j;     // A k    = (lane>>4)*8 + j
    float v   = (o < OC && hh < HID) ? w2[(o*HID + hh)*3 + tap] : 0.f;
    g_w2a[idx] = (_Float16)v;
}

// ---------------- Kernel A: conv1+GELU (VALU) -> conv2 (MFMA) -> ws ----------------
__global__ __launch_bounds__(256, 2) void mlp_kernel(
    const float* __restrict__ input,   // [2, 8, 360, 512]
    const float* __restrict__ w1,      // [176, 8, 3]
    const float* __restrict__ b1,      // [176]
    const float* __restrict__ b2,      // [88]
    __half* __restrict__ ws)
{
    const int v    = blockIdx.x;
    const int b    = blockIdx.y;
    const int tid  = threadIdx.x;
    const int lane = tid & 63;
    const int wv   = tid >> 6;     // wave 0..3 -> output cols [wv*32, wv*32+32)
    const int l15  = lane & 15;
    const int l4   = lane >> 4;

    __shared__ __align__(16) float    x_s[520][8];        // x_s[d+2][c], zero edges
    __shared__ __align__(16) _Float16 w1_s[HID][24];      // fp16 conv1 weights
    __shared__ float                  b1_s[HID];
    __shared__ __align__(16) _Float16 hT[HTROWS * HTHALF]; // swizzled, row r <-> d = d0-1+r

    // ---- one-time staging ----
    // zero hT: pad granules (hh 176..191) must stay zero forever
    {
        int4 zi = make_int4(0,0,0,0);
        for (int i = tid; i < (HTROWS*HTHALF*2)/16; i += 256) ((int4*)hT)[i] = zi;
    }
    // stage x (coalesced read), transposed into x_s[d+2][c]
    for (int j = tid; j < CH*NDET; j += 256) {
        int c = j >> 9, d = j & 511;
        x_s[d + 2][c] = input[((b*CH + c)*VIEWS + v)*NDET + d];
    }
    if (tid < 64) {
        int t = tid >> 3;
        int row = (t < 2) ? t : 512 + t;   // rows 0,1,514..519 = zero padding
        x_s[row][tid & 7] = 0.f;
    }
    for (int i = tid; i < HID*24; i += 256) w1_s[i/24][i%24] = (_Float16)w1[i];
    for (int i = tid; i < HID;    i += 256) b1_s[i] = b1[i];

    // conv2 bias in registers, laid out per C/D fragment mapping
    float accb[NMT][4];
    #pragma unroll
    for (int mt = 0; mt < NMT; ++mt)
        #pragma unroll
        for (int q = 0; q < 4; ++q) {
            int o = mt*16 + l4*4 + q;
            accb[mt][q] = (o < OC) ? b2[o] : 0.f;
        }

    __syncthreads();

    for (int chunk = 0; chunk < NCHUNK; ++chunk) {
        const int d0 = chunk * DCHUNK;

        // ---- phase 1: conv1 + exact GELU -> hT (fp16, swizzled) ----
        // item = (oct of 8 hh) x (rowgroup of 4 rows): 22*33 = 726 items
        #pragma unroll 1
        for (int it = 0; it < 3; ++it) {
            int i = it*256 + tid;
            if (i < 726) {
                int oct = i / 33;
                int rg  = i - oct*33;
                int r0  = rg * 4;                 // rows r0..r0+3 (some >=130 skipped)
                // x registers: 6 consecutive d x 8 channels
                float xr[6][8];
                #pragma unroll
                for (int k = 0; k < 6; ++k) {
                    const float4* xp = (const float4*)(&x_s[d0 + r0 + k][0]);
                    float4 xa = xp[0], xb = xp[1];
                    xr[k][0]=xa.x; xr[k][1]=xa.y; xr[k][2]=xa.z; xr[k][3]=xa.w;
                    xr[k][4]=xb.x; xr[k][5]=xb.y; xr[k][6]=xb.z; xr[k][7]=xb.w;
                }
                f16x8 hout[4];
                #pragma unroll
                for (int hsub = 0; hsub < 8; ++hsub) {
                    int hh = oct*8 + hsub;
                    const f16x8* wp = (const f16x8*)(&w1_s[hh][0]);
                    f16x8 wA = wp[0], wB = wp[1], wC = wp[2];
                    float wr[24];
                    #pragma unroll
                    for (int t = 0; t < 8; ++t) {
                        wr[t] = (float)wA[t]; wr[8+t] = (float)wB[t]; wr[16+t] = (float)wC[t];
                    }
                    float bias = b1_s[hh];
                    #pragma unroll
                    for (int rr = 0; rr < 4; ++rr) {
                        float a = bias;
                        #pragma unroll
                        for (int c = 0; c < CH; ++c) {
                            a += wr[c*3+0] * xr[rr+0][c]
                               + wr[c*3+1] * xr[rr+1][c]
                               + wr[c*3+2] * xr[rr+2][c];
                        }
                        int d = d0 - 1 + r0 + rr;
                        float g = 0.f;
                        if ((unsigned)d < (unsigned)NDET)
                            g = 0.5f * a * (1.0f + erff(a * 0.70710678118654752f));
                        hout[rr][hsub] = (_Float16)g;
                    }
                }
                #pragma unroll
                for (int rr = 0; rr < 4; ++rr) {
                    int r = r0 + rr;
                    if (r < HTROWS) {
                        int g = oct ^ swz(r);
                        *(f16x8*)(&hT[r*HTHALF + g*8]) = hout[rr];
                    }
                }
            }
        }
        __syncthreads();

        // ---- phase 2: conv2 as GEMM on MFMA ----
        f32x4 acc[NMT][2];
        #pragma unroll
        for (int mt = 0; mt < NMT; ++mt)
            #pragma unroll
            for (int nt = 0; nt < 2; ++nt)
                #pragma unroll
                for (int q = 0; q < 4; ++q)
                    acc[mt][nt][q] = accb[mt][q];

        #pragma unroll 2
        for (int kb = 0; kb < 6; ++kb) {
            #pragma unroll
            for (int tap = 0; tap < 3; ++tap) {
                const int kstep = kb*3 + tap;
                f16x8 af[NMT];
                #pragma unroll
                for (int mt = 0; mt < NMT; ++mt)
                    af[mt] = *(const f16x8*)(&g_w2a[((kstep*NMT + mt)*64 + lane)*8]);
                f16x8 bf[2];
                #pragma unroll
                for (int nt = 0; nt < 2; ++nt) {
                    int rr = wv*32 + nt*16 + l15 + tap;     // hT row = (d - d0) + tap
                    int g  = (kb*4 + l4) ^ swz(rr);
                    bf[nt] = *(const f16x8*)(&hT[rr*HTHALF + g*8]);
                }
                #pragma unroll
                for (int mt = 0; mt < NMT; ++mt)
                    #pragma unroll
                    for (int nt = 0; nt < 2; ++nt)
                        acc[mt][nt] = __builtin_amdgcn_mfma_f32_16x16x32_f16(
                            af[mt], bf[nt], acc[mt][nt], 0, 0, 0);
            }
        }

        // ---- phase 3: epilogue, scatter fp16 into ws[pos][16] ----
        #pragma unroll
        for (int mt = 0; mt < NMT; ++mt) {
            #pragma unroll
            for (int q = 0; q < 4; ++q) {
                int o = mt*16 + l4*4 + q;       // C/D row
                if (o < OC) {
                    int c = o / RR;
                    int r = o - c*RR;
                    #pragma unroll
                    for (int nt = 0; nt < 2; ++nt) {
                        int d = d0 + wv*32 + nt*16 + l15;   // C/D col
                        size_t pos = (size_t)((v*NDET + d)*RR + r);
                        ws[pos*16 + b*8 + c] = __float2half(acc[mt][nt][q]);
                    }
                }
            }
        }
        __syncthreads();
    }
}

// ---------------- Kernel B: interpolation gather (unchanged) ----------------
__global__ __launch_bounds__(256) void gather_kernel(
    const float* __restrict__ indices,
    const __half* __restrict__ ws,
    float* __restrict__ out)
{
    int i = blockIdx.x * 256 + threadIdx.x;
    if (i >= NIDX) return;

    float idx      = indices[i];
    float idx_low  = floorf(idx);
    float w        = idx - idx_low;
    float fw       = floorf(w * 5.0f);
    float low_ind  = idx_low * 11.0f + 5.0f + fw;
    float low_w    = w * 5.0f - fw;
    float high_ind = low_ind + 6.0f;
    if (high_ind >= (float)(LPOS - 1)) high_ind = (float)(LPOS - 2);
    int li = (int)low_ind;
    int hi = (int)high_ind;

    const uint4* wsv = (const uint4*)ws;   // 8 halves per uint4; 2 per position
    float omlw = 1.0f - low_w;
    float omw  = 1.0f - w;

    #pragma unroll
    for (int part = 0; part < 2; ++part) {
        uint4 A  = wsv[(size_t)li * 2 + part];
        uint4 Bv = wsv[(size_t)(li + 1) * 2 + part];
        uint4 Cv = wsv[(size_t)hi * 2 + part];
        uint4 Dv = wsv[(size_t)(hi + 1) * 2 + part];
        const __half* ah = (const __half*)&A;
        const __half* bh = (const __half*)&Bv;
        const __half* ch = (const __half*)&Cv;
        const __half* dh = (const __half*)&Dv;
        #pragma unroll
        for (int j = 0; j < 8; ++j) {
            float a  = __half2float(ah[j]);
            float bb = __half2float(bh[j]);
            float cc = __half2float(ch[j]);
            float dd = __half2float(dh[j]);
            float lo = a  * omlw + bb * low_w;
            float hv = cc * omlw + dd * low_w;
            float r  = lo * omw + hv * w;
            out[(size_t)(part * 8 + j) * NIDX + i] = r;
        }
    }
}

extern "C" void kernel_launch(void* const* d_in, const int* in_sizes, int n_in,
                              void* d_out, int out_size, void* d_ws, size_t ws_size,
                              hipStream_t stream) {
    const float* input   = (const float*)d_in[0];
    const float* indices = (const float*)d_in[1];
    const float* w1      = (const float*)d_in[2];
    const float* b1      = (const float*)d_in[3];
    const float* w2      = (const float*)d_in[4];
    const float* b2      = (const float*)d_in[5];
    __half* ws = (__half*)d_ws;
    float* out = (float*)d_out;

    pack_w2<<<dim3((NKSTEP*NMT*64*8 + 255)/256), dim3(256), 0, stream>>>(w2);
    mlp_kernel<<<dim3(VIEWS, 2), dim3(256), 0, stream>>>(input, w1, b1, b2, ws);

    int nb = (NIDX + 255) / 256;
    gather_kernel<<<dim3(nb), dim3(256), 0, stream>>>(indices, ws, out);
}

// Round 2
// 827.127 us; speedup vs baseline: 2.8395x; 1.1244x over previous
//
#include <hip/hip_runtime.h>
#include <hip/hip_fp16.h>
#include <math.h>

// ---- geometry ----
#define VIEWS  360
#define NDET   512
#define CH     8
#define RR     11
#define HID    176
#define OC     88
#define LPOS   (VIEWS*NDET*RR)       // 2,027,520 positions
#define NIDX   (128*128*VIEWS)       // 5,898,240 indices

#define DCHUNK 64
#define NCHUNK (NDET/DCHUNK)         // 8
#define HTROWS (DCHUNK+2)            // 66 rows: d = d0-1 .. d0+64
#define HTHALF 192                   // halves per hT row (24 x 16B granules, HID padded 176->192)
#define NMT    6                     // o-tiles of 16 (OC padded 88->96)
#define NKSTEP 18                    // 6 k-blocks x 3 conv taps
#define EPITCH 98                    // epilogue scratch pitch (halves), odd-ish to spread banks

typedef _Float16 f16x8 __attribute__((ext_vector_type(8)));
typedef float    f32x4 __attribute__((ext_vector_type(4)));

// w2 pre-packed in MFMA A-fragment order: [kstep][mt][lane][8], fp16, zero-padded
__device__ __align__(16) _Float16 g_w2a[NKSTEP*NMT*64*8];

// XOR swizzle on 16B granules; same function on write and read sides.
__device__ __forceinline__ int swz(int r) { return (r ^ (r >> 3)) & 7; }

// ---------------- Kernel 0: pack w2 into fragment order ----------------
__global__ __launch_bounds__(256) void pack_w2(const float* __restrict__ w2)
{
    int idx = blockIdx.x*256 + threadIdx.x;
    if (idx >= NKSTEP*NMT*64*8) return;
    int j     = idx & 7;
    int lane  = (idx >> 3) & 63;
    int t     = idx >> 9;
    int mt    = t % NMT;
    int kstep = t / NMT;
    int kb    = kstep / 3, tap = kstep % 3;
    int o     = mt*16 + (lane & 15);           // A row  = lane&15
    int hh    = kb*32 + (lane >> 4)*8 + j;     // A k    = (lane>>4)*8 + j
    float v   = (o < OC && hh < HID) ? w2[(o*HID + hh)*3 + tap] : 0.f;
    g_w2a[idx] = (_Float16)v;
}

// ---------------- Kernel A: conv1+GELU (VALU) -> conv2 (MFMA) -> ws ----------------
// LDS: x_s 16640 + w1_s 8448 + b1_s 704 + hT 25344 = 49.9 KB -> 3 blocks/CU,
// all 720 blocks resident (no tail wave).
__global__ __launch_bounds__(256, 3) void mlp_kernel(
    const float* __restrict__ input,   // [2, 8, 360, 512]
    const float* __restrict__ w1,      // [176, 8, 3]
    const float* __restrict__ b1,      // [176]
    const float* __restrict__ b2,      // [88]
    __half* __restrict__ ws)
{
    const int v    = blockIdx.x;
    const int b    = blockIdx.y;
    const int tid  = threadIdx.x;
    const int lane = tid & 63;
    const int wv   = tid >> 6;     // wave 0..3 -> output cols [wv*16, wv*16+16)
    const int l15  = lane & 15;
    const int l4   = lane >> 4;

    __shared__ __align__(16) float    x_s[520][8];        // x_s[d+2][c], zero edges
    __shared__ __align__(16) _Float16 w1_s[HID][24];      // fp16 conv1 weights
    __shared__ float                  b1_s[HID];
    __shared__ __align__(16) _Float16 hT[HTROWS * HTHALF]; // swizzled, row r <-> d = d0-1+r
    _Float16* eT = hT;   // epilogue scratch aliases hT (clobbered pad granules hit
                         // zeroed A-weights: finite*0 == 0, safe)

    // ---- one-time staging ----
    // zero hT once: k-pad granules (hh 176..191) must be finite (avoid NaN*0)
    {
        int4 zi = make_int4(0,0,0,0);
        for (int i = tid; i < (HTROWS*HTHALF*2)/16; i += 256) ((int4*)hT)[i] = zi;
    }
    // stage x (coalesced read), transposed into x_s[d+2][c]
    for (int j = tid; j < CH*NDET; j += 256) {
        int c = j >> 9, d = j & 511;
        x_s[d + 2][c] = input[((b*CH + c)*VIEWS + v)*NDET + d];
    }
    if (tid < 64) {
        int t = tid >> 3;
        int row = (t < 2) ? t : 512 + t;   // rows 0,1,514..519 = zero padding
        x_s[row][tid & 7] = 0.f;
    }
    for (int i = tid; i < HID*24; i += 256) w1_s[i/24][i%24] = (_Float16)w1[i];
    for (int i = tid; i < HID;    i += 256) b1_s[i] = b1[i];

    // conv2 bias in registers, laid out per C/D fragment mapping
    float accb[NMT][4];
    #pragma unroll
    for (int mt = 0; mt < NMT; ++mt)
        #pragma unroll
        for (int q = 0; q < 4; ++q) {
            int o = mt*16 + l4*4 + q;
            accb[mt][q] = (o < OC) ? b2[o] : 0.f;
        }

    __syncthreads();

    for (int chunk = 0; chunk < NCHUNK; ++chunk) {
        const int d0 = chunk * DCHUNK;

        // ---- phase 1: conv1 + exact GELU -> hT (fp16, swizzled) ----
        // item = (oct of 8 hh) x (rowgroup of 4 rows): 22*17 = 374 items
        #pragma unroll 1
        for (int it = 0; it < 2; ++it) {
            int i = it*256 + tid;
            if (i < 374) {
                int oct = i / 17;
                int rg  = i - oct*17;
                int r0  = rg * 4;                 // rows r0..r0+3 (r>=66 skipped)
                float xr[6][8];
                #pragma unroll
                for (int k = 0; k < 6; ++k) {
                    const float4* xp = (const float4*)(&x_s[d0 + r0 + k][0]);
                    float4 xa = xp[0], xb = xp[1];
                    xr[k][0]=xa.x; xr[k][1]=xa.y; xr[k][2]=xa.z; xr[k][3]=xa.w;
                    xr[k][4]=xb.x; xr[k][5]=xb.y; xr[k][6]=xb.z; xr[k][7]=xb.w;
                }
                f16x8 hout[4];
                #pragma unroll
                for (int hsub = 0; hsub < 8; ++hsub) {
                    int hh = oct*8 + hsub;
                    const f16x8* wp = (const f16x8*)(&w1_s[hh][0]);
                    f16x8 wA = wp[0], wB = wp[1], wC = wp[2];
                    float wr[24];
                    #pragma unroll
                    for (int t = 0; t < 8; ++t) {
                        wr[t] = (float)wA[t]; wr[8+t] = (float)wB[t]; wr[16+t] = (float)wC[t];
                    }
                    float bias = b1_s[hh];
                    #pragma unroll
                    for (int rr = 0; rr < 4; ++rr) {
                        float a = bias;
                        #pragma unroll
                        for (int c = 0; c < CH; ++c) {
                            a += wr[c*3+0] * xr[rr+0][c]
                               + wr[c*3+1] * xr[rr+1][c]
                               + wr[c*3+2] * xr[rr+2][c];
                        }
                        int d = d0 - 1 + r0 + rr;
                        float g = 0.f;
                        if ((unsigned)d < (unsigned)NDET)
                            g = 0.5f * a * (1.0f + erff(a * 0.70710678118654752f));
                        hout[rr][hsub] = (_Float16)g;
                    }
                }
                #pragma unroll
                for (int rr = 0; rr < 4; ++rr) {
                    int r = r0 + rr;
                    if (r < HTROWS) {
                        int g = oct ^ swz(r);
                        *(f16x8*)(&hT[r*HTHALF + g*8]) = hout[rr];
                    }
                }
            }
        }
        __syncthreads();

        // ---- phase 2: conv2 as GEMM on MFMA ----
        f32x4 acc[NMT];
        #pragma unroll
        for (int mt = 0; mt < NMT; ++mt)
            #pragma unroll
            for (int q = 0; q < 4; ++q)
                acc[mt][q] = accb[mt][q];

        #pragma unroll 3
        for (int kb = 0; kb < 6; ++kb) {
            #pragma unroll
            for (int tap = 0; tap < 3; ++tap) {
                const int kstep = kb*3 + tap;
                f16x8 af[NMT];
                #pragma unroll
                for (int mt = 0; mt < NMT; ++mt)
                    af[mt] = *(const f16x8*)(&g_w2a[((kstep*NMT + mt)*64 + lane)*8]);
                int rr = wv*16 + l15 + tap;         // hT row = (d - d0) + tap
                int g  = (kb*4 + l4) ^ swz(rr);
                f16x8 bf = *(const f16x8*)(&hT[rr*HTHALF + g*8]);
                #pragma unroll
                for (int mt = 0; mt < NMT; ++mt)
                    acc[mt] = __builtin_amdgcn_mfma_f32_16x16x32_f16(
                        af[mt], bf, acc[mt], 0, 0, 0);
            }
        }
        __syncthreads();   // all hT reads done before eT (alias) is written

        // ---- phase 3a: stage acc into eT[d][o] (halves) ----
        {
            int d16 = wv*16 + l15;
            #pragma unroll
            for (int mt = 0; mt < NMT; ++mt) {
                #pragma unroll
                for (int q = 0; q < 4; ++q) {
                    int o = mt*16 + l4*4 + q;
                    eT[d16*EPITCH + o] = (_Float16)acc[mt][q];
                }
            }
        }
        __syncthreads();

        // ---- phase 3b: repack + coalesced 16B stores to ws[pos][16] ----
        // item j over 64 d x 11 r = 704 stores of f16x8 at ws half-offset pos*16 + b*8
        #pragma unroll 1
        for (int it = 0; it < 3; ++it) {
            int j = it*256 + tid;
            if (j < 704) {
                int d = (j * 2979) >> 15;          // j/11 exact for j<704
                int r = j - d*11;
                f16x8 val;
                #pragma unroll
                for (int c = 0; c < CH; ++c)
                    val[c] = eT[d*EPITCH + c*11 + r];
                size_t pos = (size_t)((v*NDET + d0 + d)*RR + r);
                *(f16x8*)((__half*)ws + pos*16 + b*8) = val;
            }
        }
        __syncthreads();   // eT reads done before next chunk's phase 1 rewrites hT
    }
}

// ---------------- Kernel B: interpolation gather ----------------
__global__ __launch_bounds__(256) void gather_kernel(
    const float* __restrict__ indices,
    const __half* __restrict__ ws,
    float* __restrict__ out)
{
    int i = blockIdx.x * 256 + threadIdx.x;
    if (i >= NIDX) return;

    float idx      = __builtin_nontemporal_load(&indices[i]);
    float idx_low  = floorf(idx);
    float w        = idx - idx_low;
    float fw       = floorf(w * 5.0f);
    float low_ind  = idx_low * 11.0f + 5.0f + fw;
    float low_w    = w * 5.0f - fw;
    float high_ind = low_ind + 6.0f;
    if (high_ind >= (float)(LPOS - 1)) high_ind = (float)(LPOS - 2);
    int li = (int)low_ind;
    int hi = (int)high_ind;

    const uint4* wsv = (const uint4*)ws;   // 8 halves per uint4; 2 per position
    float omlw = 1.0f - low_w;
    float omw  = 1.0f - w;

    #pragma unroll
    for (int part = 0; part < 2; ++part) {
        uint4 A  = wsv[(size_t)li * 2 + part];
        uint4 Bv = wsv[(size_t)(li + 1) * 2 + part];
        uint4 Cv = wsv[(size_t)hi * 2 + part];
        uint4 Dv = wsv[(size_t)(hi + 1) * 2 + part];
        const __half* ah = (const __half*)&A;
        const __half* bh = (const __half*)&Bv;
        const __half* ch = (const __half*)&Cv;
        const __half* dh = (const __half*)&Dv;
        #pragma unroll
        for (int j = 0; j < 8; ++j) {
            float a  = __half2float(ah[j]);
            float bb = __half2float(bh[j]);
            float cc = __half2float(ch[j]);
            float dd = __half2float(dh[j]);
            float lo = a  * omlw + bb * low_w;
            float hv = cc * omlw + dd * low_w;
            float r  = lo * omw + hv * w;
            // non-temporal: out is write-once streaming; keep L2 for ws reuse
            __builtin_nontemporal_store(r, &out[(size_t)(part * 8 + j) * NIDX + i]);
        }
    }
}

extern "C" void kernel_launch(void* const* d_in, const int* in_sizes, int n_in,
                              void* d_out, int out_size, void* d_ws, size_t ws_size,
                              hipStream_t stream) {
    const float* input   = (const float*)d_in[0];
    const float* indices = (const float*)d_in[1];
    const float* w1      = (const float*)d_in[2];
    const float* b1      = (const float*)d_in[3];
    const float* w2      = (const float*)d_in[4];
    const float* b2      = (const float*)d_in[5];
    __half* ws = (__half*)d_ws;
    float* out = (float*)d_out;

    pack_w2<<<dim3((NKSTEP*NMT*64*8 + 255)/256), dim3(256), 0, stream>>>(w2);
    mlp_kernel<<<dim3(VIEWS, 2), dim3(256), 0, stream>>>(input, w1, b1, b2, ws);

    int nb = (NIDX + 255) / 256;
    gather_kernel<<<dim3(nb), dim3(256), 0, stream>>>(indices, ws, out);
}